// Round 5
// baseline (213.534 us; speedup 1.0000x reference)
//
#include <hip/hip_runtime.h>
#include <hip/hip_bf16.h>

#define I_DIM 4096
#define J_DIM 4096
#define NPERM0 10
#define NPERM1 10
#define RROWS 4            // output rows per block
#define FUSED_THREADS 512  // each thread owns 8 consecutive columns

typedef float          f32x4 __attribute__((ext_vector_type(4)));
typedef int            i32x4 __attribute__((ext_vector_type(4)));
typedef unsigned short u16x8 __attribute__((ext_vector_type(8)));

// XOR-swizzle on f32x4 index: spreads stride-4 b128 accesses over all 8
// bank-groups. Bijective on [0,4096).
__device__ __forceinline__ int swz(int idx) { return idx ^ ((idx >> 3) & 7); }

// bf16 -> f32: shift into high half.
__device__ __forceinline__ float bf2f(unsigned short u) {
    return __uint_as_float((unsigned)u << 16);
}
// f32 -> bf16 with round-to-nearest-even.
__device__ __forceinline__ unsigned short f2bf(float f) {
    unsigned u = __float_as_uint(f);
    u += 0x7FFFu + ((u >> 16) & 1u);
    return (unsigned short)(u >> 16);
}

// soft mask: clip((xi-gamma)*sigmoid(x)+gamma, 0, 1) with xi=1.1, gamma=-0.1
__device__ __forceinline__ float soft_mask(float x) {
    float s = 1.0f / (1.0f + __expf(-x));
    return fminf(fmaxf(1.2f * s - 0.1f, 0.0f), 1.0f);
}

// Pass 0: sw = bf16(weight * soft_mask(sparse_mask)).
// 8 elements/thread: 2x f32x4 NT loads of each input, one 16B bf16 store.
// weight/mask single-use -> NT loads keep them out of L2/L3; sw is re-read
// 10x by the fused pass -> regular (cached) store.
__global__ __launch_bounds__(256) void sw_kernel(
    const float* __restrict__ w, const float* __restrict__ m,
    unsigned short* __restrict__ swb, int n8) {
    int idx = blockIdx.x * blockDim.x + threadIdx.x;
    if (idx >= n8) return;
    const f32x4* w4 = reinterpret_cast<const f32x4*>(w) + 2 * (size_t)idx;
    const f32x4* m4 = reinterpret_cast<const f32x4*>(m) + 2 * (size_t)idx;
    f32x4 w0 = __builtin_nontemporal_load(w4);
    f32x4 w1 = __builtin_nontemporal_load(w4 + 1);
    f32x4 m0 = __builtin_nontemporal_load(m4);
    f32x4 m1 = __builtin_nontemporal_load(m4 + 1);
    u16x8 o;
#pragma unroll
    for (int k = 0; k < 4; ++k) {
        o[k]     = f2bf(w0[k] * soft_mask(m0[k]));
        o[k + 4] = f2bf(w1[k] * soft_mask(m1[k]));
    }
    reinterpret_cast<u16x8*>(swb)[idx] = o;
}

// Fused pass: per block, RROWS=4 output rows; thread t owns columns 8t..8t+7.
//   Phase A (row-mix): v[r][c] = sum_p ps0[p,i_r] * sw[perm0[p,i_r], c]
//     sw rows loaded as bf16x8 (16B/lane), accumulated in f32.
//     LDS layout [c] -> f32x4 (r0..r3), XOR-swizzled index.
//   Phase B (col-mix): out[i_r][c] = sum_q v[r][perm1[q,c]] * ps1[q,c]
//     one swizzled ds_read_b128 per (q,c) yields all 4 rows.
__global__ __launch_bounds__(FUSED_THREADS, 4) void fused_kernel(
    const unsigned short* __restrict__ swb,
    const float* __restrict__ ps0,   // (NPERM0, I)
    const float* __restrict__ ps1,   // (NPERM1, J)
    const int*   __restrict__ perm0, // (NPERM0, I)
    const int*   __restrict__ perm1, // (NPERM1, J)
    float* __restrict__ out) {
    __shared__ f32x4 vlds[J_DIM];    // 64 KiB, [c] -> (r0,r1,r2,r3)

    const int i0 = blockIdx.x * RROWS;
    const int c8 = threadIdx.x;      // column-octet index, 0..511

    // ---- Phase A ----
    float acc[RROWS][8];
#pragma unroll
    for (int r = 0; r < RROWS; ++r)
#pragma unroll
        for (int k = 0; k < 8; ++k) acc[r][k] = 0.f;

#pragma unroll
    for (int p = 0; p < NPERM0; ++p) {
#pragma unroll
        for (int r = 0; r < RROWS; ++r) {
            int   row = perm0[p * I_DIM + i0 + r];   // block-uniform -> scalar
            float s   = ps0 [p * I_DIM + i0 + r];    // block-uniform -> scalar
            u16x8 v   = reinterpret_cast<const u16x8*>(
                            swb + (size_t)row * J_DIM)[c8];
#pragma unroll
            for (int k = 0; k < 8; ++k) acc[r][k] += s * bf2f(v[k]);
        }
    }
    // Transpose to [c][r] and write 8 swizzled b128 stores (conflict-free:
    // for fixed k, swz index %8 = k^(lane&7), uniform over bank groups).
#pragma unroll
    for (int k = 0; k < 8; ++k) {
        f32x4 t;
        t[0] = acc[0][k]; t[1] = acc[1][k]; t[2] = acc[2][k]; t[3] = acc[3][k];
        vlds[swz(8 * c8 + k)] = t;
    }
    __syncthreads();

    // ---- Phase B ----
    float o[RROWS][8];
#pragma unroll
    for (int r = 0; r < RROWS; ++r)
#pragma unroll
        for (int k = 0; k < 8; ++k) o[r][k] = 0.f;

#pragma unroll
    for (int q = 0; q < NPERM1; ++q) {
        const i32x4* pq = reinterpret_cast<const i32x4*>(perm1 + (size_t)q * J_DIM);
        const f32x4* sq = reinterpret_cast<const f32x4*>(ps1  + (size_t)q * J_DIM);
        i32x4 pc0 = pq[2 * c8];
        i32x4 pc1 = pq[2 * c8 + 1];
        f32x4 s0  = sq[2 * c8];
        f32x4 s1  = sq[2 * c8 + 1];
#pragma unroll
        for (int k = 0; k < 4; ++k) {
            f32x4 va = vlds[swz(pc0[k])];
            f32x4 vb = vlds[swz(pc1[k])];
#pragma unroll
            for (int r = 0; r < RROWS; ++r) {
                o[r][k]     += s0[k] * va[r];
                o[r][k + 4] += s1[k] * vb[r];
            }
        }
    }
#pragma unroll
    for (int r = 0; r < RROWS; ++r) {
        f32x4* dst = reinterpret_cast<f32x4*>(out + (size_t)(i0 + r) * J_DIM) + 2 * c8;
        f32x4 t0, t1;
#pragma unroll
        for (int k = 0; k < 4; ++k) { t0[k] = o[r][k]; t1[k] = o[r][k + 4]; }
        dst[0] = t0;   // regular cached stores: L2 write-combines full lines
        dst[1] = t1;
    }
}

extern "C" void kernel_launch(void* const* d_in, const int* in_sizes, int n_in,
                              void* d_out, int out_size, void* d_ws, size_t ws_size,
                              hipStream_t stream) {
    const float* weight = (const float*)d_in[0];
    const float* smask  = (const float*)d_in[1];
    const float* ps0    = (const float*)d_in[2];
    const float* ps1    = (const float*)d_in[3];
    const int*   perm0  = (const int*)d_in[4];
    const int*   perm1  = (const int*)d_in[5];
    float* out = (float*)d_out;
    unsigned short* swb = (unsigned short*)d_ws;  // I*J*2 = 32 MiB scratch

    const int n8 = I_DIM * J_DIM / 8;
    sw_kernel<<<n8 / 256, 256, 0, stream>>>(weight, smask, swb, n8);
    fused_kernel<<<I_DIM / RROWS, FUSED_THREADS, 0, stream>>>(
        swb, ps0, ps1, perm0, perm1, out);
}

// Round 6
// 95.413 us; speedup vs baseline: 2.2380x; 2.2380x over previous
//
#include <hip/hip_runtime.h>
#include <hip/hip_bf16.h>

#define I_DIM 4096
#define J_DIM 4096
#define NPERM0 10
#define NPERM1 10
#define RROWS 4            // output rows per block
#define FUSED_THREADS 512  // each thread owns 8 consecutive columns

typedef float          f32x4 __attribute__((ext_vector_type(4)));
typedef int            i32x4 __attribute__((ext_vector_type(4)));
typedef unsigned short u16x8 __attribute__((ext_vector_type(8)));

// XOR-swizzle on f32x4 index: for the phase-A write (idx = 8*c8+k, fixed k)
// consecutive lanes hit all 8 bank-group offsets -> conflict-free b128.
__device__ __forceinline__ int swz(int idx) { return idx ^ ((idx >> 3) & 7); }

// bf16 -> f32: shift into high half.
__device__ __forceinline__ float bf2f(unsigned short u) {
    return __uint_as_float((unsigned)u << 16);
}
// f32 -> bf16 round-to-nearest-even.
__device__ __forceinline__ unsigned short f2bf(float f) {
    unsigned u = __float_as_uint(f);
    u += 0x7FFFu + ((u >> 16) & 1u);
    return (unsigned short)(u >> 16);
}

// soft mask: clip((xi-gamma)*sigmoid(x)+gamma, 0, 1) with xi=1.1, gamma=-0.1
__device__ __forceinline__ float soft_mask(float x) {
    float s = 1.0f / (1.0f + __expf(-x));
    return fminf(fmaxf(1.2f * s - 0.1f, 0.0f), 1.0f);
}

// Pass 0: sw = bf16(weight * soft_mask(sparse_mask)).
// weight/mask single-use -> NT loads; sw re-read 10x -> cached store.
__global__ __launch_bounds__(256) void sw_kernel(
    const float* __restrict__ w, const float* __restrict__ m,
    unsigned short* __restrict__ swb, int n8) {
    int idx = blockIdx.x * blockDim.x + threadIdx.x;
    if (idx >= n8) return;
    const f32x4* w4 = reinterpret_cast<const f32x4*>(w) + 2 * (size_t)idx;
    const f32x4* m4 = reinterpret_cast<const f32x4*>(m) + 2 * (size_t)idx;
    f32x4 w0 = __builtin_nontemporal_load(w4);
    f32x4 w1 = __builtin_nontemporal_load(w4 + 1);
    f32x4 m0 = __builtin_nontemporal_load(m4);
    f32x4 m1 = __builtin_nontemporal_load(m4 + 1);
    u16x8 o;
#pragma unroll
    for (int k = 0; k < 4; ++k) {
        o[k]     = f2bf(w0[k] * soft_mask(m0[k]));
        o[k + 4] = f2bf(w1[k] * soft_mask(m1[k]));
    }
    reinterpret_cast<u16x8*>(swb)[idx] = o;
}

// Fused pass: per block, RROWS=4 output rows; thread t owns columns 8t..8t+7.
//   Phase A (row-mix): acc[r][c] = sum_p ps0[p,i_r] * sw[perm0[p,i_r], c]
//   Phase B (col-mix): out[i_r][c] = sum_q v[r][perm1[q,c]] * ps1[q,c]
// launch_bounds(512,2): allow >=128 VGPRs (LDS already caps at 2 blocks/CU);
// unroll 2 on the p/q loops keeps live state ~100 VGPRs -> NO SPILL
// (round-5 post-mortem: spill was the 340MB write amplification).
__global__ __launch_bounds__(FUSED_THREADS, 2) void fused_kernel(
    const unsigned short* __restrict__ swb,
    const float* __restrict__ ps0,   // (NPERM0, I)
    const float* __restrict__ ps1,   // (NPERM1, J)
    const int*   __restrict__ perm0, // (NPERM0, I)
    const int*   __restrict__ perm1, // (NPERM1, J)
    float* __restrict__ out) {
    __shared__ f32x4 vlds[J_DIM];    // 64 KiB, [c] -> (r0,r1,r2,r3)

    const int i0 = blockIdx.x * RROWS;
    const int c8 = threadIdx.x;      // column-octet index, 0..511

    // ---- Phase A ----
    float acc[RROWS][8];
#pragma unroll
    for (int r = 0; r < RROWS; ++r)
#pragma unroll
        for (int k = 0; k < 8; ++k) acc[r][k] = 0.f;

#pragma unroll 2
    for (int p = 0; p < NPERM0; ++p) {
        u16x8 v[RROWS];
#pragma unroll
        for (int r = 0; r < RROWS; ++r) {
            int row = perm0[p * I_DIM + i0 + r];   // block-uniform -> s_load
            v[r] = reinterpret_cast<const u16x8*>(swb + (size_t)row * J_DIM)[c8];
        }
#pragma unroll
        for (int r = 0; r < RROWS; ++r) {
            float s = ps0[p * I_DIM + i0 + r];     // block-uniform -> s_load
#pragma unroll
            for (int k = 0; k < 8; ++k) acc[r][k] += s * bf2f(v[r][k]);
        }
    }
    // Transpose to [c][r]; swizzled, conflict-free b128 stores.
#pragma unroll
    for (int k = 0; k < 8; ++k) {
        f32x4 t;
        t[0] = acc[0][k]; t[1] = acc[1][k]; t[2] = acc[2][k]; t[3] = acc[3][k];
        vlds[swz(8 * c8 + k)] = t;
    }
    __syncthreads();

    // ---- Phase B ----
    float o[RROWS][8];
#pragma unroll
    for (int r = 0; r < RROWS; ++r)
#pragma unroll
        for (int k = 0; k < 8; ++k) o[r][k] = 0.f;

#pragma unroll 2
    for (int q = 0; q < NPERM1; ++q) {
        const i32x4* pq = reinterpret_cast<const i32x4*>(perm1 + (size_t)q * J_DIM);
        const f32x4* sq = reinterpret_cast<const f32x4*>(ps1  + (size_t)q * J_DIM);
        i32x4 pc0 = pq[2 * c8];
        i32x4 pc1 = pq[2 * c8 + 1];
        f32x4 s0  = sq[2 * c8];
        f32x4 s1  = sq[2 * c8 + 1];
        f32x4 g[8];
#pragma unroll
        for (int k = 0; k < 4; ++k) {
            g[k]     = vlds[swz(pc0[k])];
            g[k + 4] = vlds[swz(pc1[k])];
        }
#pragma unroll
        for (int k = 0; k < 4; ++k) {
#pragma unroll
            for (int r = 0; r < RROWS; ++r) {
                o[r][k]     += s0[k] * g[k][r];
                o[r][k + 4] += s1[k] * g[k + 4][r];
            }
        }
    }
#pragma unroll
    for (int r = 0; r < RROWS; ++r) {
        f32x4 t0, t1;
#pragma unroll
        for (int k = 0; k < 4; ++k) { t0[k] = o[r][k]; t1[k] = o[r][k + 4]; }
        f32x4* dst = reinterpret_cast<f32x4*>(out + (size_t)(i0 + r) * J_DIM) + 2 * c8;
        dst[0] = t0;   // cached stores: full-line write-combining in L2
        dst[1] = t1;
    }
}

extern "C" void kernel_launch(void* const* d_in, const int* in_sizes, int n_in,
                              void* d_out, int out_size, void* d_ws, size_t ws_size,
                              hipStream_t stream) {
    const float* weight = (const float*)d_in[0];
    const float* smask  = (const float*)d_in[1];
    const float* ps0    = (const float*)d_in[2];
    const float* ps1    = (const float*)d_in[3];
    const int*   perm0  = (const int*)d_in[4];
    const int*   perm1  = (const int*)d_in[5];
    float* out = (float*)d_out;
    unsigned short* swb = (unsigned short*)d_ws;  // I*J*2 = 32 MiB scratch

    const int n8 = I_DIM * J_DIM / 8;
    sw_kernel<<<n8 / 256, 256, 0, stream>>>(weight, smask, swb, n8);
    fused_kernel<<<I_DIM / RROWS, FUSED_THREADS, 0, stream>>>(
        swb, ps0, ps1, perm0, perm1, out);
}